// Round 11
// baseline (243.307 us; speedup 1.0000x reference)
//
#include <hip/hip_runtime.h>

// ---------------------------------------------------------------------------
// ZSSR involution net, fp32. Round 11: one dispatch per layer (8 total).
// inv_kernel: WG = one 8x8 tile, ALL 64 ch (t computed once -- no R9-style
// redundancy). Phases: stage halo -> t (from LDS) -> w in REGISTERS -> einsum.
// Layout: x[4 g][136x136 padded px][16 ch] channel-last, 3-px zero border.
// Band swizzle: wid&7 = XCD band, fixed across layers (R10 win, kept).
// ---------------------------------------------------------------------------

#define HH 130
#define SP 136               // padded row stride
#define PPL (SP*SP)          // 18496
#define GP (PPL*16)          // floats per group-plane
#define XBUF2 (4*GP)         // floats per feature buffer

// --- conv_in (3->64, 3x3, pad=2) + border zeroing of both ping-pong bufs ---
__global__ __launch_bounds__(256) void conv_in_kernel(
        const float* __restrict__ inf, const float* __restrict__ W,
        const float* __restrict__ b, float* __restrict__ x0,
        float* __restrict__ x1) {
    const int tid = threadIdx.x;
    if (blockIdx.x >= 67) {
        int idx = ((blockIdx.x - 67)*4 + blockIdx.y)*256 + tid;
        if (idx < 3192) {                      // 1596 border px * 2 buffers
            int bsel = idx & 1, e = idx >> 1;
            int r, c;
            if (e < 816) { r = e/136; c = e%136; if (r >= 3) r += 130; }
            else { int j = e-816; r = 3 + j/6; int m = j%6; c = (m<3)? m : m+130; }
            float* base = (bsel ? x1 : x0) + ((size_t)r*SP + c)*16;
            float4 z = make_float4(0.f,0.f,0.f,0.f);
            #pragma unroll
            for (int g2 = 0; g2 < 4; ++g2)
                #pragma unroll
                for (int q = 0; q < 4; ++q)
                    *(float4*)(base + (size_t)g2*GP + q*4) = z;
        }
        return;
    }
    __shared__ float wl[448];          // [16 ch][27 taps] + bias[16]
    const int g = blockIdx.y;
    for (int i = tid; i < 448; i += 256)
        wl[i] = (i < 432) ? W[g*432 + i] : b[g*16 + (i-432)];
    __syncthreads();
    int px = blockIdx.x*256 + tid;
    int pxc = px < 16900 ? px : 16899;
    int h = pxc/130, w = pxc%130;
    float xv[27];
    #pragma unroll
    for (int i = 0; i < 3; ++i)
      #pragma unroll
      for (int ky = 0; ky < 3; ++ky) {
        int y = h - 2 + ky;
        #pragma unroll
        for (int kx = 0; kx < 3; ++kx) {
            int xx = w - 2 + kx;
            float v = 0.f;
            if ((unsigned)y < 128u && (unsigned)xx < 128u)
                v = inf[i*16384 + y*128 + xx];
            xv[i*9 + ky*3 + kx] = v;
        }
      }
    float acc[16];
    #pragma unroll
    for (int c = 0; c < 16; ++c) {
        float a = wl[432 + c];
        #pragma unroll
        for (int t = 0; t < 27; ++t) a += wl[c*27 + t] * xv[t];
        acc[c] = a;
    }
    if (px < 16900) {
        float* dst = x0 + (size_t)g*GP + ((size_t)(h+3)*SP + (w+3))*16;
        #pragma unroll
        for (int q = 0; q < 4; ++q)
            *(float4*)(dst + q*4) =
                make_float4(acc[q*4], acc[q*4+1], acc[q*4+2], acc[q*4+3]);
    }
}

// --- inv_kernel: full involution layer, one WG per 8x8 tile ----------------
// grid 296 (wid&7 = band, wid>>3 = slot; T = band*37+slot, 289 used).
// 256 thr. Phase A: stage 64-ch halo (14x14) to LDS. Phase B: t[16] per px
// (thread = (px, r-quad wave), x from LDS, redw s_load). Phase C: per-thread
// (px, group-wave) w[49] in REGISTERS from spanw s_loads; einsum 196 b128.
// LDS: xl[16][14][14][4] 50176 B + tl[16][64] 4096 B = 54272 B -> 3 WGs/CU.
__global__ __launch_bounds__(256, 3) void inv_kernel(
        const float* __restrict__ x,
        const float* __restrict__ redw,   // [16][64]
        const float* __restrict__ gamma, const float* __restrict__ beta,
        const float* __restrict__ spanw,  // [4 g][49 k][16 r]
        const float* __restrict__ spanb,  // [4 g][49]
        float* __restrict__ xout)
{
    __shared__ float xl[16][14][14][4];   // [qq=g*4+q][r][c][e]
    __shared__ float tl[16][64];          // [r][px]
    const int tid = threadIdx.x;
    const int wid = blockIdx.x;
    const int T = (wid & 7)*37 + (wid >> 3);
    if (T >= 289) return;
    const int ty = (T/17)*8, tx = (T%17)*8;
    const int px = tid & 63;
    const int wv = __builtin_amdgcn_readfirstlane(tid >> 6);
    const int sr = px >> 3, sc = px & 7;

    // ---- Phase A: stage halo, all 64 ch, coalesced float4 ----
    for (int i = tid; i < 3136; i += 256) {
        int q = i & 3, rest = i >> 2;          // rest 0..783
        int g2 = rest / 196, p = rest % 196;
        int r = p / 14, c = p % 14;
        int gr = ty + r, gc = tx + c;
        gr = gr < SP ? gr : SP-1;              // clamp lands in zero border
        gc = gc < SP ? gc : SP-1;
        float4 v = *(const float4*)(x + (size_t)g2*GP
                                    + ((size_t)gr*SP + gc)*16 + q*4);
        *(float4*)&xl[g2*4 + q][r][c][0] = v;
    }
    __syncthreads();

    // ---- Phase B: t (thread = (px, r-quad wave)), x from LDS center ----
    {
        const float* rw = redw + wv*4*64;      // wave-uniform -> s_load
        float a0=0.f, a1=0.f, a2=0.f, a3=0.f;
        #pragma unroll
        for (int qq = 0; qq < 16; ++qq) {
            float4 v = *(const float4*)&xl[qq][sr+3][sc+3][0];
            const int c = (qq>>2)*16 + (qq&3)*4;
            a0 += rw[c+0]*v.x   + rw[c+1]*v.y   + rw[c+2]*v.z   + rw[c+3]*v.w;
            a1 += rw[64+c]*v.x  + rw[65+c]*v.y  + rw[66+c]*v.z  + rw[67+c]*v.w;
            a2 += rw[128+c]*v.x + rw[129+c]*v.y + rw[130+c]*v.z + rw[131+c]*v.w;
            a3 += rw[192+c]*v.x + rw[193+c]*v.y + rw[194+c]*v.z + rw[195+c]*v.w;
        }
        const int r0 = wv*4;
        tl[r0+0][px] = fmaxf(gamma[r0+0]*a0 + beta[r0+0], 0.f);
        tl[r0+1][px] = fmaxf(gamma[r0+1]*a1 + beta[r0+1], 0.f);
        tl[r0+2][px] = fmaxf(gamma[r0+2]*a2 + beta[r0+2], 0.f);
        tl[r0+3][px] = fmaxf(gamma[r0+3]*a3 + beta[r0+3], 0.f);
    }
    __syncthreads();

    // ---- Phase C: w[49] in registers (thread = (px, group wave)) ----
    const int g = wv;
    float t16[16];
    #pragma unroll
    for (int r = 0; r < 16; ++r) t16[r] = tl[r][px];   // conflict-free b32

    const float* sw = spanw + g*784;           // wave-uniform -> s_load
    const float* sb = spanb + g*49;
    float wk[49];
    #pragma unroll
    for (int k = 0; k < 49; ++k) {
        float a = sb[k];
        #pragma unroll
        for (int r = 0; r < 16; ++r) a += sw[k*16 + r] * t16[r];
        wk[k] = a;
    }

    // ---- einsum: 49 taps x 16 ch (this wave's group), all LDS b128 ----
    float4 acc[4] = {make_float4(0.f,0.f,0.f,0.f), make_float4(0.f,0.f,0.f,0.f),
                     make_float4(0.f,0.f,0.f,0.f), make_float4(0.f,0.f,0.f,0.f)};
    #pragma unroll
    for (int i = 0; i < 7; ++i)
        #pragma unroll
        for (int j = 0; j < 7; ++j) {
            float wv4 = wk[i*7 + j];
            #pragma unroll
            for (int q = 0; q < 4; ++q) {
                float4 xv = *(const float4*)&xl[g*4 + q][sr + i][sc + j][0];
                acc[q].x += wv4*xv.x; acc[q].y += wv4*xv.y;
                acc[q].z += wv4*xv.z; acc[q].w += wv4*xv.w;
            }
        }

    const int h = ty + sr, w = tx + sc;
    if (h < HH && w < HH) {
        float* dst = xout + (size_t)g*GP + ((size_t)(h+3)*SP + (w+3))*16;
        #pragma unroll
        for (int q = 0; q < 4; ++q) {
            float4 o;
            o.x = fmaxf(acc[q].x, 0.f); o.y = fmaxf(acc[q].y, 0.f);
            o.z = fmaxf(acc[q].z, 0.f); o.w = fmaxf(acc[q].w, 0.f);
            *(float4*)(dst + q*4) = o;
        }
    }
}

// --- conv_out (64->12, 3x3 valid) + PixelShuffle(2) ------------------------
__global__ __launch_bounds__(256) void conv_out_ps_kernel(
        const float* __restrict__ x, const float* __restrict__ W,
        const float* __restrict__ b, float* __restrict__ out)
{
    __shared__ float xh[64*120];   // [c][10 r][12 cl]
    __shared__ float wl[6912];     // 12*64*9
    const int tid = threadIdx.x;
    const int ty = blockIdx.y*8, tx = blockIdx.x*8;

    for (int idx = tid; idx < 6912; idx += 256) wl[idx] = W[idx];
    for (int idx = tid; idx < 1600; idx += 256) {
        int g = idx/400, rem = idx%400;
        int p100 = rem>>2, q = rem&3;
        int r = p100/10, cl = p100%10;
        float4 v = *(const float4*)(x + (size_t)g*GP
                     + ((size_t)(ty + r + 3)*SP + tx + cl + 3)*16 + q*4);
        int c0 = g*16 + q*4;
        xh[(c0+0)*120 + r*12 + cl] = v.x;
        xh[(c0+1)*120 + r*12 + cl] = v.y;
        xh[(c0+2)*120 + r*12 + cl] = v.z;
        xh[(c0+3)*120 + r*12 + cl] = v.w;
    }
    __syncthreads();

    const int wave = __builtin_amdgcn_readfirstlane(tid >> 6);
    const int lane = tid & 63;
    const int s = lane >> 2, cq = lane & 3;
    const int sr = s >> 1, pc0 = (s & 1)*4;
    float acc[3][4] = {};

    for (int c = cq*16; c < cq*16 + 16; ++c) {
        #pragma unroll
        for (int ky = 0; ky < 3; ++ky) {
            const float* xb = &xh[c*120 + (sr + ky)*12 + pc0];
            float4 xa = *(const float4*)xb;
            float2 xm = *(const float2*)(xb + 4);
            float xr[6] = {xa.x, xa.y, xa.z, xa.w, xm.x, xm.y};
            #pragma unroll
            for (int oj = 0; oj < 3; ++oj) {
                const float* wp = &wl[((wave*3 + oj)*64 + c)*9 + ky*3];
                #pragma unroll
                for (int kx = 0; kx < 3; ++kx) {
                    float wv = wp[kx];
                    #pragma unroll
                    for (int q = 0; q < 4; ++q)
                        acc[oj][q] += wv * xr[kx + q];
                }
            }
        }
    }

    #pragma unroll
    for (int oj = 0; oj < 3; ++oj)
        #pragma unroll
        for (int q = 0; q < 4; ++q) {
            float v = acc[oj][q];
            v += __shfl_xor(v, 1, 64);
            v += __shfl_xor(v, 2, 64);
            acc[oj][q] = v;
        }

    if (cq == 0) {
        #pragma unroll
        for (int oj = 0; oj < 3; ++oj) {
            int o = wave*3 + oj;
            float bo = b[o];
            int c3 = o >> 2, r = (o >> 1) & 1, s2 = o & 1;
            int h = ty + sr;
            #pragma unroll
            for (int q = 0; q < 4; ++q) {
                int w = tx + pc0 + q;
                out[c3*65536 + (2*h + r)*256 + 2*w + s2] = acc[oj][q] + bo;
            }
        }
    }
}

// ---------------------------------------------------------------------------
extern "C" void kernel_launch(void* const* d_in, const int* in_sizes, int n_in,
                              void* d_out, int out_size, void* d_ws, size_t ws_size,
                              hipStream_t stream) {
    const float* inf   = (const float*)d_in[0];
    const float* cinw  = (const float*)d_in[1];
    const float* cinb  = (const float*)d_in[2];
    const float* redw  = (const float*)d_in[3];
    const float* gam   = (const float*)d_in[4];
    const float* bet   = (const float*)d_in[5];
    const float* spw   = (const float*)d_in[6];
    const float* spb   = (const float*)d_in[7];
    const float* cow   = (const float*)d_in[8];
    const float* cob   = (const float*)d_in[9];

    float* ws = (float*)d_ws;
    float* x0 = ws;
    float* x1 = ws + XBUF2;

    conv_in_kernel<<<dim3(80, 4), 256, 0, stream>>>(inf, cinw, cinb, x0, x1);

    float* cur = x0; float* nxt = x1;
    for (int l = 0; l < 6; ++l) {
        inv_kernel<<<296, 256, 0, stream>>>(
            cur, redw + l*1024, gam + l*16, bet + l*16,
            spw + l*3136, spb + l*196, nxt);
        float* t = cur; cur = nxt; nxt = t;
    }

    conv_out_ps_kernel<<<dim3(16, 16), 256, 0, stream>>>(
        cur, cow, cob, (float*)d_out);
}